// Round 10
// baseline (407.903 us; speedup 1.0000x reference)
//
#include <hip/hip_runtime.h>

typedef unsigned short u16;
typedef unsigned int u32;
typedef __attribute__((ext_vector_type(4))) float f32x4;
typedef __bf16 bf16x8 __attribute__((ext_vector_type(8)));

#define DI __device__ __forceinline__

DI u16 f2bf(float f) { return __builtin_bit_cast(u16, (__bf16)f); }
DI float bf2f(u16 h) {
  unsigned u = ((unsigned)h) << 16;
  return __builtin_bit_cast(float, u);
}
DI u32 pk2(float a, float b) {
  return (u32)__builtin_bit_cast(u16, (__bf16)a) |
         ((u32)__builtin_bit_cast(u16, (__bf16)b) << 16);
}
DI f32x4 mfma16(bf16x8 a, bf16x8 b, f32x4 c) {
  return __builtin_amdgcn_mfma_f32_16x16x32_bf16(a, b, c, 0, 0, 0);
}
DI void gload_lds16(const void* g, void* l) {
  __builtin_amdgcn_global_load_lds(
      (const __attribute__((address_space(1))) u32*)g,
      (__attribute__((address_space(3))) u32*)l, 16, 0, 0);
}

// Problem constants: B=16 T=12 N=512 D=96 G=4 S=10 K_T=3
// hTt layout: [b][s][d][m] with m = k*512+n   (160*96*1536 bf16)
// cat layout: [b][s][n][c], c in [0,384) = Hk cols only (X0 fused into k3)

// ---------------- K1: h = relu(Xw @ Wu^T), write hTt transposed -------------
// grid 3840 = 160(b,s) * 8(n-tile 64) * 3(k). block 256 (4 waves). (R2 exact)
__global__ __launch_bounds__(256) void k1(const float* __restrict__ X,
                                          const float* __restrict__ Wu,
                                          u16* __restrict__ hTt) {
  __shared__ u16 As[64 * 296];   // Xw tile [n=64][c=288] (+8 pad)
  __shared__ u16 Bs[96 * 296];   // Wu rows [j=96][c=288]
  __shared__ u16 Ts[64 * 100];   // transpose buffer [n][d]
  const int wg = blockIdx.x;
  const int kk = wg % 3;
  const int n0 = ((wg / 3) & 7) * 64;
  const int bs = wg / 24;
  const int b = bs / 10, s = bs % 10;
  const int tid = threadIdx.x;

#pragma unroll
  for (int i = 0; i < 18; ++i) {
    int idx = tid + i * 256;          // < 4608 = 64*72
    int r = idx / 72, q = idx % 72;
    int kq = q / 24, dq = q % 24;
    const float4 v = *reinterpret_cast<const float4*>(
        &X[(((b * 12) + s + kq) * 512 + (n0 + r)) * 96 + dq * 4]);
    uint2 u; u.x = pk2(v.x, v.y); u.y = pk2(v.z, v.w);
    *reinterpret_cast<uint2*>(&As[r * 296 + q * 4]) = u;
  }
#pragma unroll
  for (int i = 0; i < 27; ++i) {
    int idx = tid + i * 256;          // < 6912 = 96*72
    int j = idx / 72, q = idx % 72;
    const float4 v = *reinterpret_cast<const float4*>(
        &Wu[(kk * 96 + j) * 288 + q * 4]);
    uint2 u; u.x = pk2(v.x, v.y); u.y = pk2(v.z, v.w);
    *reinterpret_cast<uint2*>(&Bs[j * 296 + q * 4]) = u;
  }
  __syncthreads();

  const int w = tid >> 6, l = tid & 63;
  const int lr = l & 15, lk = (l >> 4) * 8;
  f32x4 acc[6] = {};
#pragma unroll
  for (int ks = 0; ks < 9; ++ks) {
    bf16x8 a = *reinterpret_cast<const bf16x8*>(&As[(w * 16 + lr) * 296 + ks * 32 + lk]);
#pragma unroll
    for (int ct = 0; ct < 6; ++ct) {
      bf16x8 bb = *reinterpret_cast<const bf16x8*>(&Bs[(ct * 16 + lr) * 296 + ks * 32 + lk]);
      acc[ct] = mfma16(a, bb, acc[ct]);
    }
  }
  const int rowb = w * 16 + (l >> 4) * 4;
#pragma unroll
  for (int ct = 0; ct < 6; ++ct) {
#pragma unroll
    for (int rg = 0; rg < 4; ++rg) {
      float v = acc[ct][rg];
      v = v > 0.f ? v : 0.f;
      Ts[(rowb + rg) * 100 + ct * 16 + lr] = f2bf(v);
    }
  }
  __syncthreads();
  const int obase = bs * 96 * 1536 + kk * 512 + n0;
#pragma unroll
  for (int i = 0; i < 24; ++i) {
    int idx = tid + i * 256;          // < 6144 = 96*64
    int d = idx >> 6, n = idx & 63;
    hTt[obase + d * 1536 + n] = Ts[n * 100 + d];
  }
}

// ---------------- K2: Hk einsum -> cat384[..., g*96 + d] --------------------
// Per b: Out[(g,n),(s,d)] = sum_m dyn[g,b,n,m] * hTt[b,s,d,m]
// NEW REGIME TEST: many small desynced blocks. Block 128(rows) x 96(cols:
// one s-slice), BK=64, 24 steps, SINGLE-buffered LDS 28KB. 256 thr / 4 waves
// (2wm x 2wn), wave tile 64x48 (acc 4x3 = 48 VGPR, spill-safe at 102 cap).
// 5 blocks/CU = 20 waves/CU in 5 independent barrier domains; exposed
// per-step staging is covered by sibling-block TLP (the only lever that has
// moved k2 across R2-R9). Grid 2560 = exactly 2 occupancy rounds.
// Swizzle: proven 64-col-row (r&7)<<3 (0 conflicts). B via gload_lds,
// pre-swizzled source, linear wave-uniform dest.
__global__ __launch_bounds__(256, 5) void k2(const float* __restrict__ dyn,
                                             const u16* __restrict__ hTt,
                                             u16* __restrict__ cat) {
  __shared__ u16 As[128 * 64];   // dyn tile [n=128][m=64] bf16, 16 KB
  __shared__ u16 Bs[96 * 64];    // hTt tile [d=96][m=64] bf16, 12 KB
  const int wg0 = blockIdx.x;
  const int wg = (wg0 & 7) * 320 + (wg0 >> 3);   // bijective XCD swizzle (2560%8==0)
  const int s = wg % 10;
  const int rt = (wg / 10) & 15;
  const int b = wg / 160;
  const int g = rt >> 2, n0 = (rt & 3) * 128;

  const int tid = threadIdx.x;
  const int w = tid >> 6, l = tid & 63;
  const int wm = w & 1, wn = w >> 1;
  const int lr = l & 15, q = l >> 4;
  const int sw = (lr & 7) << 3;

  const long abase = (long)((g * 16 + b) * 512 + n0) * 1536;
  const long bbase = (long)((b * 10 + s) * 96) * 1536;

  // A staging: 128 rows x 64 k-cols fp32; thread: row ar=tid>>1, 32-col half.
  // Two passes of 16 floats (4 dwordx4 in flight -> low VGPR pressure).
  const int ar = tid >> 1, ah = (tid & 1) * 32;
  const float* aptr = &dyn[abase + (long)ar * 1536 + ah];
  const int ars = (ar & 7) << 3;

  // B staging: 12 gload_lds issues of 1KB (8 rows x 128B); 3 per wave.
  // issue idx e = w*3+j: rows e*8 + (l>>3); lane col pre-swizzled.
  const int brow_l = l >> 3;
  const int bcol = ((l & 7) ^ brow_l) * 8;

  f32x4 acc[2][3] = {};   // acc[mi-pair]? -> acc[4][3] flattened as 2x2 below
  f32x4 acc2[2][3] = {};  // keep two named halves (static indexing, rule #20)

  auto stage = [&](int t) {
    // B async direct-to-LDS (in flight across A's load+cvt)
#pragma unroll
    for (int j = 0; j < 3; ++j) {
      const int e = w * 3 + j;
      const u16* src = &hTt[bbase + (long)(e * 8 + brow_l) * 1536 + t * 64 + bcol];
      gload_lds16(src, &Bs[e * 512]);   // wave-uniform linear dest
    }
    // A: two passes of 4 dwordx4 -> cvt_pk -> swizzled ds_write_b128 x2
#pragma unroll
    for (int p = 0; p < 2; ++p) {
      const float* pp = aptr + (long)t * 64 + p * 16;
      float4 a0 = *reinterpret_cast<const float4*>(pp);
      float4 a1 = *reinterpret_cast<const float4*>(pp + 4);
      float4 a2 = *reinterpret_cast<const float4*>(pp + 8);
      float4 a3 = *reinterpret_cast<const float4*>(pp + 12);
      uint4 v0, v1;
      v0.x = pk2(a0.x, a0.y); v0.y = pk2(a0.z, a0.w);
      v0.z = pk2(a1.x, a1.y); v0.w = pk2(a1.z, a1.w);
      v1.x = pk2(a2.x, a2.y); v1.y = pk2(a2.z, a2.w);
      v1.z = pk2(a3.x, a3.y); v1.w = pk2(a3.z, a3.w);
      *reinterpret_cast<uint4*>(&As[ar * 64 + ((ah + p * 16) ^ ars)]) = v0;
      *reinterpret_cast<uint4*>(&As[ar * 64 + ((ah + p * 16 + 8) ^ ars)]) = v1;
    }
  };
  auto compute = [&]() {
    __builtin_amdgcn_s_setprio(1);
#pragma unroll
    for (int ks = 0; ks < 2; ++ks) {
      const int ko = (ks * 32 + q * 8) ^ sw;
      bf16x8 a0 = *reinterpret_cast<const bf16x8*>(&As[(wm * 64 +  0 + lr) * 64 + ko]);
      bf16x8 a1 = *reinterpret_cast<const bf16x8*>(&As[(wm * 64 + 16 + lr) * 64 + ko]);
      bf16x8 a2 = *reinterpret_cast<const bf16x8*>(&As[(wm * 64 + 32 + lr) * 64 + ko]);
      bf16x8 a3 = *reinterpret_cast<const bf16x8*>(&As[(wm * 64 + 48 + lr) * 64 + ko]);
#pragma unroll
      for (int ct = 0; ct < 3; ++ct) {
        bf16x8 bb = *reinterpret_cast<const bf16x8*>(&Bs[(wn * 48 + ct * 16 + lr) * 64 + ko]);
        acc[0][ct]  = mfma16(a0, bb, acc[0][ct]);
        acc[1][ct]  = mfma16(a1, bb, acc[1][ct]);
        acc2[0][ct] = mfma16(a2, bb, acc2[0][ct]);
        acc2[1][ct] = mfma16(a3, bb, acc2[1][ct]);
      }
    }
    __builtin_amdgcn_s_setprio(0);
  };

  stage(0);
  __syncthreads();   // drains gloads + lgkm
#pragma unroll 1
  for (int t = 0; t < 24; ++t) {
    compute();
    if (t < 23) {
      __syncthreads();   // LDS consumption done, safe to overwrite
      stage(t + 1);
      __syncthreads();   // staging (incl. B DMA) complete
    }
  }

  // Epilogue: cat384[b, s, n0 + wm*64 + mi*16 + row, g*96 + wn*48 + ct*16 + lr]
  const long cb = (long)((b * 10 + s) * 512 + n0 + wm * 64) * 384 + g * 96 + wn * 48;
#pragma unroll
  for (int mi = 0; mi < 2; ++mi) {
#pragma unroll
    for (int ct = 0; ct < 3; ++ct) {
      const int d = ct * 16 + lr;
#pragma unroll
      for (int rg = 0; rg < 4; ++rg) {
        const int row0 = mi * 16 + q * 4 + rg;
        cat[cb + (long)row0 * 384 + d] = f2bf(acc[mi][ct][rg]);
        cat[cb + (long)(row0 + 32) * 384 + d] = f2bf(acc2[mi][ct][rg]);
      }
    }
  }
}

// ------- K3: out = [X0 | Hk] @ Wg^T + bias, X0 = mean_k(hTt) fused ---------
// grid 640 = 160(b,s) * 4(n-chunk 128). block 256 (4 waves). (R9 exact)
__global__ __launch_bounds__(256) void k3(const u16* __restrict__ hTt,
                                          const u16* __restrict__ cat,
                                          const float* __restrict__ Wg,
                                          const float* __restrict__ bias,
                                          float* __restrict__ out) {
  __shared__ u16 As[128 * 104];  // A tile [r=128][c=96] (+8 pad)
  __shared__ u16 Bs[96 * 104];   // Wg rows [do=96][c=96]
  const int bs = blockIdx.x >> 2;
  const int nc = (blockIdx.x & 3) * 128;
  const long row0 = (long)bs * 512 + nc;
  const int tid = threadIdx.x;
  const int w = tid >> 6, l = tid & 63;
  const int lr = l & 15, lk = (l >> 4) * 8;
  f32x4 acc[2][6] = {};

#pragma unroll 1
  for (int cc = 0; cc < 5; ++cc) {
    if (cc == 0) {
      // As[n][d] = mean_k hTt[bs][d][k*512 + nc + n]
#pragma unroll
      for (int j = 0; j < 6; ++j) {
        int o = tid + j * 256;          // < 1536 = 96*16
        int d = o >> 4, oc = o & 15;
        float a8[8] = {0.f, 0.f, 0.f, 0.f, 0.f, 0.f, 0.f, 0.f};
#pragma unroll
        for (int k = 0; k < 3; ++k) {
          const uint4 v = *reinterpret_cast<const uint4*>(
              &hTt[(bs * 96 + d) * 1536 + k * 512 + nc + oc * 8]);
          a8[0] += bf2f((u16)(v.x & 0xffffu)); a8[1] += bf2f((u16)(v.x >> 16));
          a8[2] += bf2f((u16)(v.y & 0xffffu)); a8[3] += bf2f((u16)(v.y >> 16));
          a8[4] += bf2f((u16)(v.z & 0xffffu)); a8[5] += bf2f((u16)(v.z >> 16));
          a8[6] += bf2f((u16)(v.w & 0xffffu)); a8[7] += bf2f((u16)(v.w >> 16));
        }
#pragma unroll
        for (int e = 0; e < 8; ++e)
          As[(oc * 8 + e) * 104 + d] = f2bf(a8[e] * (1.f / 3.f));
      }
    } else {
#pragma unroll
      for (int i = 0; i < 12; ++i) {
        int idx = tid + i * 256;        // < 3072 = 128*24
        int r = idx / 24, q = idx % 24;
        const ushort4 v = *reinterpret_cast<const ushort4*>(
            &cat[(row0 + r) * 384 + (cc - 1) * 96 + q * 4]);
        *reinterpret_cast<ushort4*>(&As[r * 104 + q * 4]) = v;
      }
    }
#pragma unroll
    for (int i = 0; i < 9; ++i) {
      int idx = tid + i * 256;          // < 2304 = 96*24
      int j = idx / 24, q = idx % 24;
      const float4 v = *reinterpret_cast<const float4*>(&Wg[j * 480 + cc * 96 + q * 4]);
      uint2 u; u.x = pk2(v.x, v.y); u.y = pk2(v.z, v.w);
      *reinterpret_cast<uint2*>(&Bs[j * 104 + q * 4]) = u;
    }
    __syncthreads();
#pragma unroll
    for (int ks = 0; ks < 3; ++ks) {
      bf16x8 a0 = *reinterpret_cast<const bf16x8*>(&As[(w * 32 + lr) * 104 + ks * 32 + lk]);
      bf16x8 a1 = *reinterpret_cast<const bf16x8*>(&As[(w * 32 + 16 + lr) * 104 + ks * 32 + lk]);
#pragma unroll
      for (int ct = 0; ct < 6; ++ct) {
        bf16x8 bb = *reinterpret_cast<const bf16x8*>(&Bs[(ct * 16 + lr) * 104 + ks * 32 + lk]);
        acc[0][ct] = mfma16(a0, bb, acc[0][ct]);
        acc[1][ct] = mfma16(a1, bb, acc[1][ct]);
      }
    }
    __syncthreads();
  }
#pragma unroll
  for (int rt2 = 0; rt2 < 2; ++rt2) {
    const long r = row0 + w * 32 + rt2 * 16 + (l >> 4) * 4;
#pragma unroll
    for (int ct = 0; ct < 6; ++ct) {
      const int dd = ct * 16 + lr;
      const float bv = bias[dd];
#pragma unroll
      for (int rg = 0; rg < 4; ++rg)
        out[(r + rg) * 96 + dd] = acc[rt2][ct][rg] + bv;
    }
  }
}

extern "C" void kernel_launch(void* const* d_in, const int* in_sizes, int n_in,
                              void* d_out, int out_size, void* d_ws, size_t ws_size,
                              hipStream_t stream) {
  const float* X    = (const float*)d_in[0];
  const float* dyn  = (const float*)d_in[1];
  const float* Wu   = (const float*)d_in[2];
  const float* Wg   = (const float*)d_in[3];
  const float* bias = (const float*)d_in[4];
  float* out = (float*)d_out;

  const size_t hTt_elems = (size_t)160 * 96 * 1536;   // 23,592,960
  const size_t cat_elems = (size_t)81920 * 384;       // 31,457,280
  if (ws_size < (hTt_elems + cat_elems) * sizeof(u16)) return;
  u16* hTt = (u16*)d_ws;
  u16* cat = hTt + hTt_elems;

  hipLaunchKernelGGL(k1, dim3(3840), dim3(256), 0, stream, X, Wu, hTt);
  hipLaunchKernelGGL(k2, dim3(2560), dim3(256), 0, stream, dyn, hTt, cat);
  hipLaunchKernelGGL(k3, dim3(640),  dim3(256), 0, stream, hTt, cat, Wg, bias, out);
}